// Round 2
// baseline (767.155 us; speedup 1.0000x reference)
//
#include <hip/hip_runtime.h>
#include <hip/hip_bf16.h>
#include <hip/hip_cooperative_groups.h>

namespace cg = cooperative_groups;

// ---------------------------------------------------------------------------
// EdgeFtLayer fused kernel for MI355X (gfx950).  Round 5.
//
// vs round 4 (357us fused, regression):
//   * Epilogue REVERTED to round-3 LDS two-pass segmented reduce (round-4's
//     per-4-row register flush was 2.6x the atomics -> +155MB HBM writes).
//   * Keep async swizzled global_load_lds gather; DMA addresses now loaded
//     per-lane straight from global (clamped), killing the pre-DMA barrier.
//   * B-fragment double-buffer prefetch: kc+1's 5 global loads issue before
//     kc's 20 MFMAs; mt-outer MFMA order hides ds_read latency.
//   * Native __bf16 casts for edge_attr fragment (v_cvt_pk_bf16_f32).
//   * Dispatches 10 -> 4: prep_kernel {zero num/den/cnt + x->bf16 + B-pack},
//     cooperative sort_kernel {hist, scan x3, scatter} with grid.sync(),
//     fused, finalize (vectorized).
// ---------------------------------------------------------------------------

typedef float  f32x4   __attribute__((ext_vector_type(4)));
typedef __bf16 bf16x8  __attribute__((ext_vector_type(8)));
typedef unsigned short ushort8_t __attribute__((ext_vector_type(8)));

#define RED_STRIDE 132  // f32 elems: 128 + 4 pad (quarters land on distinct banks)

__device__ __forceinline__ unsigned short f2bf(float f) {
  unsigned int u = __float_as_uint(f);
  return (unsigned short)((u + 0x7FFFu + ((u >> 16) & 1u)) >> 16);
}

__device__ __forceinline__ void store_bf4(unsigned short* p, float4 v) {
  ushort4 u;
  u.x = f2bf(v.x); u.y = f2bf(v.y); u.z = f2bf(v.z); u.w = f2bf(v.w);
  *(ushort4*)p = u;
}

// async 16B global -> LDS (dest = wave-uniform base + lane*16)
__device__ __forceinline__ void async16(void* lds, const void* g) {
  __builtin_amdgcn_global_load_lds(
      (const __attribute__((address_space(1))) unsigned int*)g,
      (__attribute__((address_space(3))) unsigned int*)lds, 16, 0, 0);
}

// ---------------------------------------------------------------------------
// K1: zero num/den/cnt + x->bf16 + pack B (block-range partitioned)
// ---------------------------------------------------------------------------
__global__ void prep_kernel(const float* __restrict__ x,
                            const float* __restrict__ Wa,
                            const float* __restrict__ Wt,
                            const float* __restrict__ We,
                            const float* __restrict__ Wee,
                            float4* __restrict__ zbase,      // num..den, N*64 float4
                            int4*   __restrict__ cnt4,       // NB*64 int4
                            unsigned short* __restrict__ xb,
                            unsigned short* __restrict__ Bp,
                            int N, int NB) {
  const int tid = threadIdx.x;
  const int zb  = (N * 64 + 255) >> 8;
  const int cb  = (NB * 64 + 255) >> 8;
  const int xbn = (N * 32 + 255) >> 8;
  int b = blockIdx.x;
  if (b < zb) {
    int i = b * 256 + tid;
    if (i < N * 64) { float4 z = {0.f, 0.f, 0.f, 0.f}; zbase[i] = z; }
    return;
  }
  b -= zb;
  if (b < cb) {
    int i = b * 256 + tid;
    if (i < NB * 64) { int4 z = {0, 0, 0, 0}; cnt4[i] = z; }
    return;
  }
  b -= cb;
  if (b < xbn) {
    int i = b * 256 + tid;
    if (i < N * 32) {
      float4 v = ((const float4*)x)[i];
      store_bf4(&xb[(size_t)i * 4], v);
    }
    return;
  }
  b -= xbn;
  {  // B pack: 400 blocks, pe in [0, 102400)
    int pe = b * 256 + tid;
    int j    = pe & 7;
    int lane = (pe >> 3) & 63;
    int kt   = (pe >> 9) % 10;
    int nt   = pe / 5120;
    int k = kt * 32 + ((lane >> 4) << 3) + j;
    int n = nt * 16 + (lane & 15);
    float v;
    if (n < 128) {
      v = Wa[k * 128 + n];
    } else if (n < 256) {
      v = Wt[k * 128 + (n - 128)];
    } else {
      int c = n - 256;
      if (k < 128)      v = We[k * 64 + c];
      else if (k < 192) v = Wee[(k - 128) * 64 + c];
      else              v = We[(k - 192) * 64 + c];
    }
    Bp[pe] = f2bf(v);
  }
}

// ---------------------------------------------------------------------------
// K2: cooperative counting-sort by dst: hist -> 3-phase scan -> scatter
// ---------------------------------------------------------------------------
__global__ void sort_kernel(const int* __restrict__ ei,
                            int* __restrict__ cnt, int* __restrict__ cur,
                            int* __restrict__ bsum,
                            int* __restrict__ eid_s, int* __restrict__ src_s,
                            int* __restrict__ dst_s, int E, int N, int NB) {
  cg::grid_group grid = cg::this_grid();
  __shared__ int ls[256];
  const int tid = threadIdx.x;
  const int g = blockIdx.x * 256 + tid;
  const int gthreads = gridDim.x * 256;

  // phase 1: histogram
  for (int e = g; e < E; e += gthreads)
    atomicAdd(&cnt[ei[E + e]], 1);
  grid.sync();

  // phase 2a: per-block sums
  if (blockIdx.x < NB) {
    int i = blockIdx.x * 256 + tid;
    ls[tid] = (i < N) ? cnt[i] : 0;
    __syncthreads();
    for (int off = 128; off > 0; off >>= 1) {
      if (tid < off) ls[tid] += ls[tid + off];
      __syncthreads();
    }
    if (tid == 0) bsum[blockIdx.x] = ls[0];
  }
  grid.sync();

  // phase 2b: exclusive scan of bsum (block 0, NB <= 256)
  if (blockIdx.x == 0) {
    int v = (tid < NB) ? bsum[tid] : 0;
    ls[tid] = v;
    __syncthreads();
    for (int off = 1; off < 256; off <<= 1) {
      int u = (tid >= off) ? ls[tid - off] : 0;
      __syncthreads();
      ls[tid] += u;
      __syncthreads();
    }
    if (tid < NB) bsum[tid] = ls[tid] - v;
  }
  grid.sync();

  // phase 2c: per-block exclusive scan + block offset -> cur
  if (blockIdx.x < NB) {
    int i = blockIdx.x * 256 + tid;
    int v = (i < N) ? cnt[i] : 0;
    ls[tid] = v;
    __syncthreads();
    for (int off = 1; off < 256; off <<= 1) {
      int u = (tid >= off) ? ls[tid - off] : 0;
      __syncthreads();
      ls[tid] += u;
      __syncthreads();
    }
    if (i < N) cur[i] = ls[tid] - v + bsum[blockIdx.x];
  }
  grid.sync();

  // phase 3: scatter
  for (int e = g; e < E; e += gthreads) {
    int s = ei[e];
    int d = ei[E + e];
    int pos = atomicAdd(&cur[d], 1);
    eid_s[pos] = e;
    src_s[pos] = s;
    dst_s[pos] = d;
  }
}

// ---------------------------------------------------------------------------
// K3: fused gather + GEMM + LDS segmented-reduction epilogue.
// 64 sorted edges / block, 4 waves; wave w owns n-tiles {w, w+4, w+8, w+12, w+16}.
// ---------------------------------------------------------------------------
__global__ __launch_bounds__(256, 3) void fused_edge_kernel(
    const unsigned short* __restrict__ xb,   // bf16 x, [N,128]
    const float* __restrict__ ea,            // f32 edge_attr, [E,64]
    const int*   __restrict__ eid_s,
    const int*   __restrict__ src_s,
    const int*   __restrict__ dst_s,
    const unsigned short* __restrict__ Bp,
    float* __restrict__ num,
    float* __restrict__ den,
    float* __restrict__ out_e,
    const float* __restrict__ a_prelu,
    int E) {
  // 48KB A-region (DMA dest, dense+src-swizzled), aliased by red (33.8KB) later
  __shared__ __align__(16) char smem[64 * 128 * 2 * 2 + 64 * 64 * 4];  // 49152
  unsigned short* At_dst = (unsigned short*)smem;              // 64x128 bf16
  unsigned short* At_src = (unsigned short*)(smem + 16384);    // 64x128 bf16
  float*          Aea    = (float*)(smem + 32768);             // 64x64  f32
  float*          red    = (float*)smem;                       // 64xRED_STRIDE f32
  __shared__ int s_dst[64];
  __shared__ int s_eid[64];

  const int tid = threadIdx.x;
  const int eb  = blockIdx.x * 64;
  const int nvalid = min(64, E - eb);

  const int w  = tid >> 6;
  const int l  = tid & 63;
  const int g4 = l >> 4;          // 16-lane quarter
  const int j  = l & 15;          // dest 16B chunk within row

  // header for epilogue (runs concurrent with DMA issue below)
  if (tid < 64) {
    int q = min(eb + tid, E - 1);
    s_eid[tid] = eid_s[q];
    s_dst[tid] = dst_s[q];
  }

  // ---- async gather: per-lane global addrs (clamped), no pre-barrier ------
  // instr t covers rows [w*16 + t*4, +4); lane writes LDS base + l*16.
  // LDS slot jj of row r holds global 16B-chunk (jj ^ (r&7)).
  #pragma unroll
  for (int t = 0; t < 4; ++t) {
    int row = w * 16 + t * 4 + g4;
    int q   = min(eb + row, E - 1);
    int nd  = dst_s[q];
    int ns  = src_s[q];
    int ee  = eid_s[q];
    int cD  = j ^ (row & 7);             // swizzled global chunk
    async16(&At_dst[(w * 16 + t * 4) * 128], xb + (size_t)nd * 128 + cD * 8);
    async16(&At_src[(w * 16 + t * 4) * 128], xb + (size_t)ns * 128 + cD * 8);
    async16(&Aea   [(w * 16 + t * 4) * 64 ], ea + (size_t)ee * 64  + cD * 4);
  }
  __syncthreads();   // drains vmcnt(0): DMA + header complete

  const int lrow = l & 15;
  const ushort8_t* BpV = (const ushort8_t*)Bp;  // frag idx = (nt*10+kc)*64 + l

  f32x4 acc[4][5];
  #pragma unroll
  for (int mt = 0; mt < 4; ++mt)
    #pragma unroll
    for (int i = 0; i < 5; ++i)
      acc[mt][i] = (f32x4){0.f, 0.f, 0.f, 0.f};

  // B double-buffer: preload kc=0
  bf16x8 bv[2][5];
  #pragma unroll
  for (int i = 0; i < 5; ++i)
    bv[0][i] = __builtin_bit_cast(bf16x8, BpV[((w + 4 * i) * 10 + 0) * 64 + l]);

  #pragma unroll
  for (int kc = 0; kc < 10; ++kc) {
    const int cur_ = kc & 1;
    const int nxt_ = cur_ ^ 1;
    // prefetch kc+1 B frags (5 global loads in flight under the 20 MFMAs)
    if (kc < 9) {
      #pragma unroll
      for (int i = 0; i < 5; ++i)
        bv[nxt_][i] = __builtin_bit_cast(
            bf16x8, BpV[((w + 4 * i) * 10 + (kc + 1)) * 64 + l]);
    }
    // A fragments for this kc (issued together; mt-outer MFMA hides latency)
    bf16x8 av[4];
    #pragma unroll
    for (int mt = 0; mt < 4; ++mt) {
      int row = mt * 16 + lrow;
      int sw  = row & 7;
      if (kc < 4) {                      // x[dst], k-cols [0,128)
        int c = kc * 4 + g4;
        av[mt] = __builtin_bit_cast(
            bf16x8, *(const ushort8_t*)&At_dst[row * 128 + ((c ^ sw) << 3)]);
      } else if (kc < 6) {               // edge_attr, k-cols [128,192)
        int c0 = (kc - 4) * 8 + (g4 << 1);
        float4 f0 = *(const float4*)&Aea[row * 64 + (((c0    ) ^ sw) << 2)];
        float4 f1 = *(const float4*)&Aea[row * 64 + (((c0 + 1) ^ sw) << 2)];
        bf16x8 t;
        t[0] = (__bf16)f0.x; t[1] = (__bf16)f0.y;
        t[2] = (__bf16)f0.z; t[3] = (__bf16)f0.w;
        t[4] = (__bf16)f1.x; t[5] = (__bf16)f1.y;
        t[6] = (__bf16)f1.z; t[7] = (__bf16)f1.w;
        av[mt] = t;
      } else {                           // x[src], k-cols [192,320)
        int c = (kc - 6) * 4 + g4;
        av[mt] = __builtin_bit_cast(
            bf16x8, *(const ushort8_t*)&At_src[row * 128 + ((c ^ sw) << 3)]);
      }
    }
    #pragma unroll
    for (int mt = 0; mt < 4; ++mt)
      #pragma unroll
      for (int i = 0; i < 5; ++i)
        acc[mt][i] = __builtin_amdgcn_mfma_f32_16x16x32_bf16(
            av[mt], bv[cur_][i], acc[mt][i], 0, 0, 0);
  }

  // ------------------- epilogue -------------------
  // C layout: row = (lane>>4)*4 + reg, col = lane&15
  const float slope = a_prelu[0];
  const int rbase = g4 << 2;
  const int ccol  = l & 15;

  // ex = exp(prelu(logits))  (VALU, before the At-free barrier)
  float exv[4][2][4];
  #pragma unroll
  for (int mt = 0; mt < 4; ++mt)
    #pragma unroll
    for (int i2 = 0; i2 < 2; ++i2)
      #pragma unroll
      for (int r = 0; r < 4; ++r) {
        float lg = acc[mt][i2][r];
        exv[mt][i2][r] = __expf(lg >= 0.f ? lg : slope * lg);
      }

  // new_e_feat stores (global, overlap with other waves' tail)
  #pragma unroll
  for (int mt = 0; mt < 4; ++mt) {
    const int m0 = mt * 16 + rbase;
    #pragma unroll
    for (int r = 0; r < 4; ++r) {
      int m = m0 + r;
      if (m < nvalid)
        out_e[(size_t)s_eid[m] * 64 + w * 16 + ccol] = acc[mt][4][r];
    }
  }

  __syncthreads();   // all A-frag reads done; recycle smem as `red`

  // ---- pass 1: num = segmented sum of ex*msg over sorted-dst runs ----
  #pragma unroll
  for (int mt = 0; mt < 4; ++mt) {
    const int m0 = mt * 16 + rbase;
    #pragma unroll
    for (int i2 = 0; i2 < 2; ++i2) {
      const int c = (w + 4 * i2) * 16 + ccol;
      #pragma unroll
      for (int r = 0; r < 4; ++r)
        red[(m0 + r) * RED_STRIDE + c] = exv[mt][i2][r] * acc[mt][i2 + 2][r];
    }
  }
  __syncthreads();
  {
    const int c  = tid & 127;
    const int r0 = (tid >> 7) << 5;
    const int r1 = min(r0 + 32, nvalid);
    float sum = 0.f;
    for (int r = r0; r < r1; ++r) {
      sum += red[r * RED_STRIDE + c];
      if (r == r1 - 1 || s_dst[r + 1] != s_dst[r]) {
        unsafeAtomicAdd(&num[(size_t)s_dst[r] * 128 + c], sum);
        sum = 0.f;
      }
    }
  }
  __syncthreads();

  // ---- pass 2: den = segmented sum of ex ----
  #pragma unroll
  for (int mt = 0; mt < 4; ++mt) {
    const int m0 = mt * 16 + rbase;
    #pragma unroll
    for (int i2 = 0; i2 < 2; ++i2) {
      const int c = (w + 4 * i2) * 16 + ccol;
      #pragma unroll
      for (int r = 0; r < 4; ++r)
        red[(m0 + r) * RED_STRIDE + c] = exv[mt][i2][r];
    }
  }
  __syncthreads();
  {
    const int c  = tid & 127;
    const int r0 = (tid >> 7) << 5;
    const int r1 = min(r0 + 32, nvalid);
    float sum = 0.f;
    for (int r = r0; r < r1; ++r) {
      sum += red[r * RED_STRIDE + c];
      if (r == r1 - 1 || s_dst[r + 1] != s_dst[r]) {
        unsafeAtomicAdd(&den[(size_t)s_dst[r] * 128 + c], sum);
        sum = 0.f;
      }
    }
  }
}

// ---------------------------------------------------------------------------
// K4: finalize (vectorized)
// ---------------------------------------------------------------------------
__global__ void finalize_kernel(const float4* __restrict__ num4,
                                const float4* __restrict__ den4,
                                const float4* __restrict__ bT4,
                                float4* __restrict__ out4, int total4) {
  int i = blockIdx.x * 256 + threadIdx.x;
  if (i < total4) {
    float4 n = num4[i];
    float4 d = den4[i];
    float4 b = bT4[i & 31];
    float4 o;
    o.x = n.x / (d.x + 1e-16f) + b.x;
    o.y = n.y / (d.y + 1e-16f) + b.y;
    o.z = n.z / (d.z + 1e-16f) + b.z;
    o.w = n.w / (d.w + 1e-16f) + b.w;
    out4[i] = o;
  }
}

extern "C" void kernel_launch(void* const* d_in, const int* in_sizes, int n_in,
                              void* d_out, int out_size, void* d_ws, size_t ws_size,
                              hipStream_t stream) {
  const float* x   = (const float*)d_in[0];
  const int*   ei  = (const int*)d_in[1];
  const float* ea  = (const float*)d_in[2];
  const float* Wa  = (const float*)d_in[3];
  const float* Wt  = (const float*)d_in[4];
  const float* bT  = (const float*)d_in[5];
  const float* We  = (const float*)d_in[6];
  const float* Wee = (const float*)d_in[7];
  const float* ap  = (const float*)d_in[8];

  const int N = in_sizes[0] / 128;          // 50000
  const int E = in_sizes[1] / 2;            // 500000
  const int NB = (N + 255) / 256;           // 196

  // workspace layout (byte offsets)
  char* ws = (char*)d_ws;
  unsigned short* Bp = (unsigned short*)ws;                       // 204,800
  float* num = (float*)(ws + 204800);                             // 25.6 MB
  float* den = num + (size_t)N * 128;                             // 25.6 MB
  int* cnt   = (int*)(ws + 204800 + (size_t)N * 128 * 8);         // 200,704
  int* cur   = cnt + 50176;                                       // 200,704
  int* eid_s = cur + 50176;                                       // 2 MB
  int* src_s = eid_s + 500224;                                    // 2 MB
  int* dst_s = src_s + 500224;                                    // 2 MB
  int* bsum  = dst_s + 500224;                                    // 1 KB
  unsigned short* x_bf16 = (unsigned short*)(bsum + 256);         // 12.8 MB

  float* out_x = (float*)d_out;
  float* out_e = out_x + (size_t)N * 128;

  // K1: zero + convert + pack  (block-range partitioned)
  {
    int zb  = (N * 64 + 255) >> 8;
    int cb  = (NB * 64 + 255) >> 8;
    int xbn = (N * 32 + 255) >> 8;
    int grid = zb + cb + xbn + 400;
    prep_kernel<<<grid, 256, 0, stream>>>(x, Wa, Wt, We, Wee,
                                          (float4*)num, (int4*)cnt,
                                          x_bf16, Bp, N, NB);
  }

  // K2: cooperative counting sort (hist -> scan -> scatter)
  {
    const int* ei_ = ei;
    int* cnt_ = cnt; int* cur_ = cur; int* bsum_ = bsum;
    int* eid_ = eid_s; int* src_ = src_s; int* dst_ = dst_s;
    int E_ = E, N_ = N, NB_ = NB;
    void* args[] = {&ei_, &cnt_, &cur_, &bsum_, &eid_, &src_, &dst_,
                    &E_, &N_, &NB_};
    hipLaunchCooperativeKernel((const void*)sort_kernel, dim3(512), dim3(256),
                               args, 0, stream);
  }

  // K3: fused gather + GEMM + segmented reduce
  fused_edge_kernel<<<(E + 63) / 64, 256, 0, stream>>>(
      x_bf16, ea, eid_s, src_s, dst_s, Bp, num, den, out_e, ap, E);

  // K4: finalize
  finalize_kernel<<<(N * 32 + 255) / 256, 256, 0, stream>>>(
      (const float4*)num, (const float4*)den, (const float4*)bT,
      (float4*)d_out, N * 32);
}

// Round 3
// 524.410 us; speedup vs baseline: 1.4629x; 1.4629x over previous
//
#include <hip/hip_runtime.h>
#include <hip/hip_bf16.h>

// ---------------------------------------------------------------------------
// EdgeFtLayer fused kernel for MI355X (gfx950).  Round 6.
//
// vs round 5 (767us, regression):
//   * Cooperative sort_kernel REVERTED: 512-block coop grid made hist/scatter
//     chains of ~4 serial cross-XCD atomics/thread (273us @ 0.16% VALUBusy).
//     Back to max-TLP separate kernels: hist folded into prep mega-kernel
//     (latency-bound hist blocks overlap BW-bound convert/pack blocks),
//     scan1/2/3 tiny, scatter at 1954 blocks.
//   * Scatter payload packed: {eid,src} as one int2 8B store (was 3x4B).
//   * Fused kernel kept exactly as round 5 (measured < 270us there).
// ---------------------------------------------------------------------------

typedef float  f32x4   __attribute__((ext_vector_type(4)));
typedef __bf16 bf16x8  __attribute__((ext_vector_type(8)));
typedef unsigned short ushort8_t __attribute__((ext_vector_type(8)));

#define RED_STRIDE 132  // f32 elems: 128 + 4 pad

__device__ __forceinline__ unsigned short f2bf(float f) {
  unsigned int u = __float_as_uint(f);
  return (unsigned short)((u + 0x7FFFu + ((u >> 16) & 1u)) >> 16);
}

__device__ __forceinline__ void store_bf4(unsigned short* p, float4 v) {
  ushort4 u;
  u.x = f2bf(v.x); u.y = f2bf(v.y); u.z = f2bf(v.z); u.w = f2bf(v.w);
  *(ushort4*)p = u;
}

// async 16B global -> LDS (dest = wave-uniform base + lane*16)
__device__ __forceinline__ void async16(void* lds, const void* g) {
  __builtin_amdgcn_global_load_lds(
      (const __attribute__((address_space(1))) unsigned int*)g,
      (__attribute__((address_space(3))) unsigned int*)lds, 16, 0, 0);
}

// ---------------------------------------------------------------------------
// K1 (after memset of num/den/cnt): hist + x->bf16 + B-pack, block-partitioned.
// hist blocks first: latency-bound atomics overlap the BW-bound conversions.
// ---------------------------------------------------------------------------
__global__ void prep_kernel(const int* __restrict__ ei,
                            const float* __restrict__ x,
                            const float* __restrict__ Wa,
                            const float* __restrict__ Wt,
                            const float* __restrict__ We,
                            const float* __restrict__ Wee,
                            int* __restrict__ cnt,
                            unsigned short* __restrict__ xb,
                            unsigned short* __restrict__ Bp,
                            int E, int N) {
  const int tid = threadIdx.x;
  const int H   = (E + 255) >> 8;        // 1954 hist blocks
  const int X   = (N * 32 + 255) >> 8;   // 6250 convert blocks
  int b = blockIdx.x;
  if (b < H) {                            // histogram of dst
    int e = b * 256 + tid;
    if (e < E) atomicAdd(&cnt[ei[E + e]], 1);
    return;
  }
  b -= H;
  if (b < X) {                            // x -> bf16
    int i = b * 256 + tid;
    if (i < N * 32) {
      float4 v = ((const float4*)x)[i];
      store_bf4(&xb[(size_t)i * 4], v);
    }
    return;
  }
  b -= X;
  {                                       // B pack: 400 blocks, pe in [0,102400)
    int pe = b * 256 + tid;
    int j    = pe & 7;
    int lane = (pe >> 3) & 63;
    int kt   = (pe >> 9) % 10;
    int nt   = pe / 5120;
    int k = kt * 32 + ((lane >> 4) << 3) + j;
    int n = nt * 16 + (lane & 15);
    float v;
    if (n < 128) {
      v = Wa[k * 128 + n];
    } else if (n < 256) {
      v = Wt[k * 128 + (n - 128)];
    } else {
      int c = n - 256;
      if (k < 128)      v = We[k * 64 + c];
      else if (k < 192) v = Wee[(k - 128) * 64 + c];
      else              v = We[(k - 192) * 64 + c];
    }
    Bp[pe] = f2bf(v);
  }
}

// --------------------------- scan (3-phase) ---------------------------------
__global__ void scan1_kernel(const int* __restrict__ cnt,
                             int* __restrict__ bsum, int n) {
  __shared__ int ls[256];
  int t = threadIdx.x;
  int i = blockIdx.x * 256 + t;
  ls[t] = (i < n) ? cnt[i] : 0;
  __syncthreads();
  for (int off = 128; off > 0; off >>= 1) {
    if (t < off) ls[t] += ls[t + off];
    __syncthreads();
  }
  if (t == 0) bsum[blockIdx.x] = ls[0];
}

__global__ void scan2_kernel(int* __restrict__ bsum, int nb) {
  __shared__ int ls[256];
  int t = threadIdx.x;
  int v = (t < nb) ? bsum[t] : 0;
  ls[t] = v;
  __syncthreads();
  for (int off = 1; off < 256; off <<= 1) {
    int u = (t >= off) ? ls[t - off] : 0;
    __syncthreads();
    ls[t] += u;
    __syncthreads();
  }
  if (t < nb) bsum[t] = ls[t] - v;   // exclusive
}

__global__ void scan3_kernel(const int* __restrict__ cnt,
                             const int* __restrict__ bsum,
                             int* __restrict__ cur, int n) {
  __shared__ int ls[256];
  int t = threadIdx.x;
  int i = blockIdx.x * 256 + t;
  int v = (i < n) ? cnt[i] : 0;
  ls[t] = v;
  __syncthreads();
  for (int off = 1; off < 256; off <<= 1) {
    int u = (t >= off) ? ls[t - off] : 0;
    __syncthreads();
    ls[t] += u;
    __syncthreads();
  }
  if (i < n) cur[i] = ls[t] - v + bsum[blockIdx.x];
}

// --------------------------- scatter (max TLP) ------------------------------
__global__ void scatter_kernel(const int* __restrict__ ei, int* __restrict__ cur,
                               int2* __restrict__ se_s, int* __restrict__ dst_s,
                               int E) {
  int e = blockIdx.x * 256 + threadIdx.x;
  if (e < E) {
    int s = ei[e];
    int d = ei[E + e];
    int pos = atomicAdd(&cur[d], 1);
    int2 v; v.x = e; v.y = s;
    se_s[pos]  = v;
    dst_s[pos] = d;
  }
}

// ---------------------------------------------------------------------------
// K3: fused gather + GEMM + LDS segmented-reduction epilogue.
// 64 sorted edges / block, 4 waves; wave w owns n-tiles {w, w+4, w+8, w+12, w+16}.
// ---------------------------------------------------------------------------
__global__ __launch_bounds__(256, 3) void fused_edge_kernel(
    const unsigned short* __restrict__ xb,   // bf16 x, [N,128]
    const float* __restrict__ ea,            // f32 edge_attr, [E,64]
    const int2*  __restrict__ se_s,          // {eid, src} sorted by dst
    const int*   __restrict__ dst_s,
    const unsigned short* __restrict__ Bp,
    float* __restrict__ num,
    float* __restrict__ den,
    float* __restrict__ out_e,
    const float* __restrict__ a_prelu,
    int E) {
  // 48KB A-region (DMA dest, dense+src-swizzled), aliased by red (33.8KB) later
  __shared__ __align__(16) char smem[64 * 128 * 2 * 2 + 64 * 64 * 4];  // 49152
  unsigned short* At_dst = (unsigned short*)smem;              // 64x128 bf16
  unsigned short* At_src = (unsigned short*)(smem + 16384);    // 64x128 bf16
  float*          Aea    = (float*)(smem + 32768);             // 64x64  f32
  float*          red    = (float*)smem;                       // 64xRED_STRIDE f32
  __shared__ int s_dst[64];
  __shared__ int s_eid[64];

  const int tid = threadIdx.x;
  const int eb  = blockIdx.x * 64;
  const int nvalid = min(64, E - eb);

  const int w  = tid >> 6;
  const int l  = tid & 63;
  const int g4 = l >> 4;          // 16-lane quarter
  const int j  = l & 15;          // dest 16B chunk within row

  // header for epilogue (runs concurrent with DMA issue below)
  if (tid < 64) {
    int q = min(eb + tid, E - 1);
    int2 se = se_s[q];
    s_eid[tid] = se.x;
    s_dst[tid] = dst_s[q];
  }

  // ---- async gather: per-lane global addrs (clamped), no pre-barrier ------
  // instr t covers rows [w*16 + t*4, +4); lane writes LDS base + l*16.
  // LDS slot jj of row r holds global 16B-chunk (jj ^ (r&7)).
  #pragma unroll
  for (int t = 0; t < 4; ++t) {
    int row = w * 16 + t * 4 + g4;
    int q   = min(eb + row, E - 1);
    int2 se = se_s[q];
    int nd  = dst_s[q];
    int ns  = se.y;
    int ee  = se.x;
    int cD  = j ^ (row & 7);             // swizzled global chunk
    async16(&At_dst[(w * 16 + t * 4) * 128], xb + (size_t)nd * 128 + cD * 8);
    async16(&At_src[(w * 16 + t * 4) * 128], xb + (size_t)ns * 128 + cD * 8);
    async16(&Aea   [(w * 16 + t * 4) * 64 ], ea + (size_t)ee * 64  + cD * 4);
  }
  __syncthreads();   // drains vmcnt(0): DMA + header complete

  const int lrow = l & 15;
  const ushort8_t* BpV = (const ushort8_t*)Bp;  // frag idx = (nt*10+kc)*64 + l

  f32x4 acc[4][5];
  #pragma unroll
  for (int mt = 0; mt < 4; ++mt)
    #pragma unroll
    for (int i = 0; i < 5; ++i)
      acc[mt][i] = (f32x4){0.f, 0.f, 0.f, 0.f};

  // B double-buffer: preload kc=0
  bf16x8 bv[2][5];
  #pragma unroll
  for (int i = 0; i < 5; ++i)
    bv[0][i] = __builtin_bit_cast(bf16x8, BpV[((w + 4 * i) * 10 + 0) * 64 + l]);

  #pragma unroll
  for (int kc = 0; kc < 10; ++kc) {
    const int cur_ = kc & 1;
    const int nxt_ = cur_ ^ 1;
    // prefetch kc+1 B frags (5 global loads in flight under the 20 MFMAs)
    if (kc < 9) {
      #pragma unroll
      for (int i = 0; i < 5; ++i)
        bv[nxt_][i] = __builtin_bit_cast(
            bf16x8, BpV[((w + 4 * i) * 10 + (kc + 1)) * 64 + l]);
    }
    // A fragments for this kc
    bf16x8 av[4];
    #pragma unroll
    for (int mt = 0; mt < 4; ++mt) {
      int row = mt * 16 + lrow;
      int sw  = row & 7;
      if (kc < 4) {                      // x[dst], k-cols [0,128)
        int c = kc * 4 + g4;
        av[mt] = __builtin_bit_cast(
            bf16x8, *(const ushort8_t*)&At_dst[row * 128 + ((c ^ sw) << 3)]);
      } else if (kc < 6) {               // edge_attr, k-cols [128,192)
        int c0 = (kc - 4) * 8 + (g4 << 1);
        float4 f0 = *(const float4*)&Aea[row * 64 + (((c0    ) ^ sw) << 2)];
        float4 f1 = *(const float4*)&Aea[row * 64 + (((c0 + 1) ^ sw) << 2)];
        bf16x8 t;
        t[0] = (__bf16)f0.x; t[1] = (__bf16)f0.y;
        t[2] = (__bf16)f0.z; t[3] = (__bf16)f0.w;
        t[4] = (__bf16)f1.x; t[5] = (__bf16)f1.y;
        t[6] = (__bf16)f1.z; t[7] = (__bf16)f1.w;
        av[mt] = t;
      } else {                           // x[src], k-cols [192,320)
        int c = (kc - 6) * 4 + g4;
        av[mt] = __builtin_bit_cast(
            bf16x8, *(const ushort8_t*)&At_src[row * 128 + ((c ^ sw) << 3)]);
      }
    }
    #pragma unroll
    for (int mt = 0; mt < 4; ++mt)
      #pragma unroll
      for (int i = 0; i < 5; ++i)
        acc[mt][i] = __builtin_amdgcn_mfma_f32_16x16x32_bf16(
            av[mt], bv[cur_][i], acc[mt][i], 0, 0, 0);
  }

  // ------------------- epilogue -------------------
  // C layout: row = (lane>>4)*4 + reg, col = lane&15
  const float slope = a_prelu[0];
  const int rbase = g4 << 2;
  const int ccol  = l & 15;

  // ex = exp(prelu(logits))
  float exv[4][2][4];
  #pragma unroll
  for (int mt = 0; mt < 4; ++mt)
    #pragma unroll
    for (int i2 = 0; i2 < 2; ++i2)
      #pragma unroll
      for (int r = 0; r < 4; ++r) {
        float lg = acc[mt][i2][r];
        exv[mt][i2][r] = __expf(lg >= 0.f ? lg : slope * lg);
      }

  // new_e_feat stores
  #pragma unroll
  for (int mt = 0; mt < 4; ++mt) {
    const int m0 = mt * 16 + rbase;
    #pragma unroll
    for (int r = 0; r < 4; ++r) {
      int m = m0 + r;
      if (m < nvalid)
        out_e[(size_t)s_eid[m] * 64 + w * 16 + ccol] = acc[mt][4][r];
    }
  }

  __syncthreads();   // all A-frag reads done; recycle smem as `red`

  // ---- pass 1: num = segmented sum of ex*msg over sorted-dst runs ----
  #pragma unroll
  for (int mt = 0; mt < 4; ++mt) {
    const int m0 = mt * 16 + rbase;
    #pragma unroll
    for (int i2 = 0; i2 < 2; ++i2) {
      const int c = (w + 4 * i2) * 16 + ccol;
      #pragma unroll
      for (int r = 0; r < 4; ++r)
        red[(m0 + r) * RED_STRIDE + c] = exv[mt][i2][r] * acc[mt][i2 + 2][r];
    }
  }
  __syncthreads();
  {
    const int c  = tid & 127;
    const int r0 = (tid >> 7) << 5;
    const int r1 = min(r0 + 32, nvalid);
    float sum = 0.f;
    for (int r = r0; r < r1; ++r) {
      sum += red[r * RED_STRIDE + c];
      if (r == r1 - 1 || s_dst[r + 1] != s_dst[r]) {
        unsafeAtomicAdd(&num[(size_t)s_dst[r] * 128 + c], sum);
        sum = 0.f;
      }
    }
  }
  __syncthreads();

  // ---- pass 2: den = segmented sum of ex ----
  #pragma unroll
  for (int mt = 0; mt < 4; ++mt) {
    const int m0 = mt * 16 + rbase;
    #pragma unroll
    for (int i2 = 0; i2 < 2; ++i2) {
      const int c = (w + 4 * i2) * 16 + ccol;
      #pragma unroll
      for (int r = 0; r < 4; ++r)
        red[(m0 + r) * RED_STRIDE + c] = exv[mt][i2][r];
    }
  }
  __syncthreads();
  {
    const int c  = tid & 127;
    const int r0 = (tid >> 7) << 5;
    const int r1 = min(r0 + 32, nvalid);
    float sum = 0.f;
    for (int r = r0; r < r1; ++r) {
      sum += red[r * RED_STRIDE + c];
      if (r == r1 - 1 || s_dst[r + 1] != s_dst[r]) {
        unsafeAtomicAdd(&den[(size_t)s_dst[r] * 128 + c], sum);
        sum = 0.f;
      }
    }
  }
}

// ---------------------------------------------------------------------------
// K4: finalize (vectorized)
// ---------------------------------------------------------------------------
__global__ void finalize_kernel(const float4* __restrict__ num4,
                                const float4* __restrict__ den4,
                                const float4* __restrict__ bT4,
                                float4* __restrict__ out4, int total4) {
  int i = blockIdx.x * 256 + threadIdx.x;
  if (i < total4) {
    float4 n = num4[i];
    float4 d = den4[i];
    float4 b = bT4[i & 31];
    float4 o;
    o.x = n.x / (d.x + 1e-16f) + b.x;
    o.y = n.y / (d.y + 1e-16f) + b.y;
    o.z = n.z / (d.z + 1e-16f) + b.z;
    o.w = n.w / (d.w + 1e-16f) + b.w;
    out4[i] = o;
  }
}

extern "C" void kernel_launch(void* const* d_in, const int* in_sizes, int n_in,
                              void* d_out, int out_size, void* d_ws, size_t ws_size,
                              hipStream_t stream) {
  const float* x   = (const float*)d_in[0];
  const int*   ei  = (const int*)d_in[1];
  const float* ea  = (const float*)d_in[2];
  const float* Wa  = (const float*)d_in[3];
  const float* Wt  = (const float*)d_in[4];
  const float* bT  = (const float*)d_in[5];
  const float* We  = (const float*)d_in[6];
  const float* Wee = (const float*)d_in[7];
  const float* ap  = (const float*)d_in[8];

  const int N = in_sizes[0] / 128;          // 50000
  const int E = in_sizes[1] / 2;            // 500000
  const int NB = (N + 255) / 256;           // 196

  // workspace layout (byte offsets)
  char* ws = (char*)d_ws;
  unsigned short* Bp = (unsigned short*)ws;                       // 204,800
  float* num = (float*)(ws + 204800);                             // 25.6 MB
  float* den = num + (size_t)N * 128;                             // 25.6 MB
  int* cnt   = (int*)(ws + 204800 + (size_t)N * 128 * 8);         // 200,704
  int* cur   = cnt + 50176;                                       // 200,704
  int2* se_s = (int2*)(cur + 50176);                              // 4 MB
  int* dst_s = (int*)(se_s + 500224);                             // 2 MB
  int* bsum  = dst_s + 500224;                                    // 1 KB
  unsigned short* x_bf16 = (unsigned short*)(bsum + 256);         // 12.8 MB

  float* out_x = (float*)d_out;
  float* out_e = out_x + (size_t)N * 128;

  // zero num, den, cnt (contiguous)
  hipMemsetAsync(num, 0, (size_t)N * 128 * 8 + 50176 * sizeof(int), stream);

  // K1: hist + x->bf16 + B-pack (hist blocks first)
  {
    int H = (E + 255) >> 8;
    int X = (N * 32 + 255) >> 8;
    prep_kernel<<<H + X + 400, 256, 0, stream>>>(ei, x, Wa, Wt, We, Wee,
                                                 cnt, x_bf16, Bp, E, N);
  }

  // K2: scans (tiny)
  scan1_kernel<<<NB, 256, 0, stream>>>(cnt, bsum, N);
  scan2_kernel<<<1, 256, 0, stream>>>(bsum, NB);
  scan3_kernel<<<NB, 256, 0, stream>>>(cnt, bsum, cur, N);

  // K3: scatter at full TLP
  scatter_kernel<<<(E + 255) / 256, 256, 0, stream>>>(ei, cur, se_s, dst_s, E);

  // K4: fused gather + GEMM + segmented reduce
  fused_edge_kernel<<<(E + 63) / 64, 256, 0, stream>>>(
      x_bf16, ea, se_s, dst_s, Bp, num, den, out_e, ap, E);

  // K5: finalize
  finalize_kernel<<<(N * 32 + 255) / 256, 256, 0, stream>>>(
      (const float4*)num, (const float4*)den, (const float4*)bT,
      (float4*)d_out, N * 32);
}

// Round 4
// 484.509 us; speedup vs baseline: 1.5834x; 1.0824x over previous
//
#include <hip/hip_runtime.h>
#include <hip/hip_bf16.h>

// ---------------------------------------------------------------------------
// EdgeFtLayer fused kernel for MI355X (gfx950).  Round 7.
//
// vs round 6 (524us total, 266us fused):
//   * Epilogue rewritten: LDS two-pass segmented reduce (2 LDS round-trips,
//     5 barriers, serial 32-iter scan loops) replaced by an in-register
//     exact-run segmented reduce:
//       - wave-uniform 64-bit run-end mask via __ballot over s_dst
//       - each lane scans its 4 contiguous C-rows; complete runs flush
//         atomics immediately; partial runs chain across the 4 lane-quarters
//         via 3x __shfl_up(.,16) and across m-tiles via a register carry.
//     Unlike round 4 (flush every 4 rows, 2.6x atomics, +155MB writes),
//     flushes happen ONLY at true run ends -> fewer atomics than round 6.
//     Fused kernel now has exactly ONE barrier (post-DMA).
//   * kc=0 B-fragments preloaded BEFORE the DMA barrier (latency hidden
//     under the DMA wait).
//   * num/den zeroing folded into prep grid; memset now cnt-only (200KB).
// ---------------------------------------------------------------------------

typedef float  f32x4   __attribute__((ext_vector_type(4)));
typedef __bf16 bf16x8  __attribute__((ext_vector_type(8)));
typedef unsigned short ushort8_t __attribute__((ext_vector_type(8)));

__device__ __forceinline__ unsigned short f2bf(float f) {
  unsigned int u = __float_as_uint(f);
  return (unsigned short)((u + 0x7FFFu + ((u >> 16) & 1u)) >> 16);
}

__device__ __forceinline__ void store_bf4(unsigned short* p, float4 v) {
  ushort4 u;
  u.x = f2bf(v.x); u.y = f2bf(v.y); u.z = f2bf(v.z); u.w = f2bf(v.w);
  *(ushort4*)p = u;
}

// async 16B global -> LDS (dest = wave-uniform base + lane*16)
__device__ __forceinline__ void async16(void* lds, const void* g) {
  __builtin_amdgcn_global_load_lds(
      (const __attribute__((address_space(1))) unsigned int*)g,
      (__attribute__((address_space(3))) unsigned int*)lds, 16, 0, 0);
}

// ---------------------------------------------------------------------------
// K1 (after memset of cnt): hist + zero num/den + x->bf16 + B-pack.
// hist blocks first: latency-bound atomics overlap the BW-bound stores.
// ---------------------------------------------------------------------------
__global__ void prep_kernel(const int* __restrict__ ei,
                            const float* __restrict__ x,
                            const float* __restrict__ Wa,
                            const float* __restrict__ Wt,
                            const float* __restrict__ We,
                            const float* __restrict__ Wee,
                            int* __restrict__ cnt,
                            float4* __restrict__ zbase,   // num..den, N*64 f4
                            unsigned short* __restrict__ xb,
                            unsigned short* __restrict__ Bp,
                            int E, int N) {
  const int tid = threadIdx.x;
  const int H   = (E + 255) >> 8;        // 1954 hist blocks
  const int Z   = (N * 64 + 255) >> 8;   // 12500 zero blocks (num+den)
  const int X   = (N * 32 + 255) >> 8;   // 6250 convert blocks
  int b = blockIdx.x;
  if (b < H) {                            // histogram of dst
    int e = b * 256 + tid;
    if (e < E) atomicAdd(&cnt[ei[E + e]], 1);
    return;
  }
  b -= H;
  if (b < Z) {                            // zero num/den
    int i = b * 256 + tid;
    if (i < N * 64) { float4 z = {0.f, 0.f, 0.f, 0.f}; zbase[i] = z; }
    return;
  }
  b -= Z;
  if (b < X) {                            // x -> bf16
    int i = b * 256 + tid;
    if (i < N * 32) {
      float4 v = ((const float4*)x)[i];
      store_bf4(&xb[(size_t)i * 4], v);
    }
    return;
  }
  b -= X;
  {                                       // B pack: 400 blocks, pe in [0,102400)
    int pe = b * 256 + tid;
    int j    = pe & 7;
    int lane = (pe >> 3) & 63;
    int kt   = (pe >> 9) % 10;
    int nt   = pe / 5120;
    int k = kt * 32 + ((lane >> 4) << 3) + j;
    int n = nt * 16 + (lane & 15);
    float v;
    if (n < 128) {
      v = Wa[k * 128 + n];
    } else if (n < 256) {
      v = Wt[k * 128 + (n - 128)];
    } else {
      int c = n - 256;
      if (k < 128)      v = We[k * 64 + c];
      else if (k < 192) v = Wee[(k - 128) * 64 + c];
      else              v = We[(k - 192) * 64 + c];
    }
    Bp[pe] = f2bf(v);
  }
}

// --------------------------- scan (3-phase) ---------------------------------
__global__ void scan1_kernel(const int* __restrict__ cnt,
                             int* __restrict__ bsum, int n) {
  __shared__ int ls[256];
  int t = threadIdx.x;
  int i = blockIdx.x * 256 + t;
  ls[t] = (i < n) ? cnt[i] : 0;
  __syncthreads();
  for (int off = 128; off > 0; off >>= 1) {
    if (t < off) ls[t] += ls[t + off];
    __syncthreads();
  }
  if (t == 0) bsum[blockIdx.x] = ls[0];
}

__global__ void scan2_kernel(int* __restrict__ bsum, int nb) {
  __shared__ int ls[256];
  int t = threadIdx.x;
  int v = (t < nb) ? bsum[t] : 0;
  ls[t] = v;
  __syncthreads();
  for (int off = 1; off < 256; off <<= 1) {
    int u = (t >= off) ? ls[t - off] : 0;
    __syncthreads();
    ls[t] += u;
    __syncthreads();
  }
  if (t < nb) bsum[t] = ls[t] - v;   // exclusive
}

__global__ void scan3_kernel(const int* __restrict__ cnt,
                             const int* __restrict__ bsum,
                             int* __restrict__ cur, int n) {
  __shared__ int ls[256];
  int t = threadIdx.x;
  int i = blockIdx.x * 256 + t;
  int v = (i < n) ? cnt[i] : 0;
  ls[t] = v;
  __syncthreads();
  for (int off = 1; off < 256; off <<= 1) {
    int u = (t >= off) ? ls[t - off] : 0;
    __syncthreads();
    ls[t] += u;
    __syncthreads();
  }
  if (i < n) cur[i] = ls[t] - v + bsum[blockIdx.x];
}

// --------------------------- scatter (max TLP) ------------------------------
__global__ void scatter_kernel(const int* __restrict__ ei, int* __restrict__ cur,
                               int2* __restrict__ se_s, int* __restrict__ dst_s,
                               int E) {
  int e = blockIdx.x * 256 + threadIdx.x;
  if (e < E) {
    int s = ei[e];
    int d = ei[E + e];
    int pos = atomicAdd(&cur[d], 1);
    int2 v; v.x = e; v.y = s;
    se_s[pos]  = v;
    dst_s[pos] = d;
  }
}

// ---------------------------------------------------------------------------
// K3: fused gather + GEMM + register exact-run segmented-reduction epilogue.
// 64 sorted edges / block, 4 waves; wave w owns n-tiles {w, w+4, w+8, w+12, w+16}.
// ---------------------------------------------------------------------------
__global__ __launch_bounds__(256, 3) void fused_edge_kernel(
    const unsigned short* __restrict__ xb,   // bf16 x, [N,128]
    const float* __restrict__ ea,            // f32 edge_attr, [E,64]
    const int2*  __restrict__ se_s,          // {eid, src} sorted by dst
    const int*   __restrict__ dst_s,
    const unsigned short* __restrict__ Bp,
    float* __restrict__ num,
    float* __restrict__ den,
    float* __restrict__ out_e,
    const float* __restrict__ a_prelu,
    int E) {
  // 48KB A-region (DMA dest, dense + source-swizzled)
  __shared__ __align__(16) char smem[64 * 128 * 2 * 2 + 64 * 64 * 4];  // 49152
  unsigned short* At_dst = (unsigned short*)smem;              // 64x128 bf16
  unsigned short* At_src = (unsigned short*)(smem + 16384);    // 64x128 bf16
  float*          Aea    = (float*)(smem + 32768);             // 64x64  f32
  __shared__ int s_dst[64];
  __shared__ int s_eid[64];

  const int tid = threadIdx.x;
  const int eb  = blockIdx.x * 64;
  const int nvalid = min(64, E - eb);

  const int w  = tid >> 6;
  const int l  = tid & 63;
  const int g4 = l >> 4;          // 16-lane quarter
  const int j  = l & 15;          // dest 16B chunk within row

  // header for epilogue (runs concurrent with DMA issue below)
  if (tid < 64) {
    int q = min(eb + tid, E - 1);
    int2 se = se_s[q];
    s_eid[tid] = se.x;
    s_dst[tid] = dst_s[q];
  }

  // ---- async gather: per-lane global addrs (clamped), no pre-barrier ------
  // instr t covers rows [w*16 + t*4, +4); lane writes LDS base + l*16.
  // LDS slot jj of row r holds global 16B-chunk (jj ^ (r&7)).
  #pragma unroll
  for (int t = 0; t < 4; ++t) {
    int row = w * 16 + t * 4 + g4;
    int q   = min(eb + row, E - 1);
    int2 se = se_s[q];
    int nd  = dst_s[q];
    int ns  = se.y;
    int ee  = se.x;
    int cD  = j ^ (row & 7);             // swizzled global chunk
    async16(&At_dst[(w * 16 + t * 4) * 128], xb + (size_t)nd * 128 + cD * 8);
    async16(&At_src[(w * 16 + t * 4) * 128], xb + (size_t)ns * 128 + cD * 8);
    async16(&Aea   [(w * 16 + t * 4) * 64 ], ea + (size_t)ee * 64  + cD * 4);
  }

  const ushort8_t* BpV = (const ushort8_t*)Bp;  // frag idx = (nt*10+kc)*64 + l

  // B double-buffer: preload kc=0 BEFORE the barrier (hidden under DMA wait)
  bf16x8 bv[2][5];
  #pragma unroll
  for (int i = 0; i < 5; ++i)
    bv[0][i] = __builtin_bit_cast(bf16x8, BpV[((w + 4 * i) * 10 + 0) * 64 + l]);

  __syncthreads();   // drains vmcnt(0): DMA + header complete

  const int lrow = l & 15;

  f32x4 acc[4][5];
  #pragma unroll
  for (int mt = 0; mt < 4; ++mt)
    #pragma unroll
    for (int i = 0; i < 5; ++i)
      acc[mt][i] = (f32x4){0.f, 0.f, 0.f, 0.f};

  #pragma unroll
  for (int kc = 0; kc < 10; ++kc) {
    const int cur_ = kc & 1;
    const int nxt_ = cur_ ^ 1;
    // prefetch kc+1 B frags (5 global loads in flight under the 20 MFMAs)
    if (kc < 9) {
      #pragma unroll
      for (int i = 0; i < 5; ++i)
        bv[nxt_][i] = __builtin_bit_cast(
            bf16x8, BpV[((w + 4 * i) * 10 + (kc + 1)) * 64 + l]);
    }
    // A fragments for this kc
    bf16x8 av[4];
    #pragma unroll
    for (int mt = 0; mt < 4; ++mt) {
      int row = mt * 16 + lrow;
      int sw  = row & 7;
      if (kc < 4) {                      // x[dst], k-cols [0,128)
        int c = kc * 4 + g4;
        av[mt] = __builtin_bit_cast(
            bf16x8, *(const ushort8_t*)&At_dst[row * 128 + ((c ^ sw) << 3)]);
      } else if (kc < 6) {               // edge_attr, k-cols [128,192)
        int c0 = (kc - 4) * 8 + (g4 << 1);
        float4 f0 = *(const float4*)&Aea[row * 64 + (((c0    ) ^ sw) << 2)];
        float4 f1 = *(const float4*)&Aea[row * 64 + (((c0 + 1) ^ sw) << 2)];
        bf16x8 t;
        t[0] = (__bf16)f0.x; t[1] = (__bf16)f0.y;
        t[2] = (__bf16)f0.z; t[3] = (__bf16)f0.w;
        t[4] = (__bf16)f1.x; t[5] = (__bf16)f1.y;
        t[6] = (__bf16)f1.z; t[7] = (__bf16)f1.w;
        av[mt] = t;
      } else {                           // x[src], k-cols [192,320)
        int c = (kc - 6) * 4 + g4;
        av[mt] = __builtin_bit_cast(
            bf16x8, *(const ushort8_t*)&At_src[row * 128 + ((c ^ sw) << 3)]);
      }
    }
    #pragma unroll
    for (int mt = 0; mt < 4; ++mt)
      #pragma unroll
      for (int i = 0; i < 5; ++i)
        acc[mt][i] = __builtin_amdgcn_mfma_f32_16x16x32_bf16(
            av[mt], bv[cur_][i], acc[mt][i], 0, 0, 0);
  }

  // ------------------- epilogue (ZERO barriers) -------------------
  // C layout: row = (lane>>4)*4 + reg, col = lane&15
  const float slope = a_prelu[0];
  const int rbase = g4 << 2;
  const int ccol  = l & 15;

  // new_e_feat stores (posted early; overlap with reduce below)
  #pragma unroll
  for (int mt = 0; mt < 4; ++mt) {
    const int m0 = mt * 16 + rbase;
    #pragma unroll
    for (int r = 0; r < 4; ++r) {
      int m = m0 + r;
      if (m < nvalid)
        out_e[(size_t)s_eid[m] * 64 + w * 16 + ccol] = acc[mt][4][r];
    }
  }

  // ---- wave-uniform run-end mask: bit k set iff row k ends its dst-run ----
  {
    int dme = s_dst[l];
    int dnx = (l < 63) ? s_dst[l + 1] : dme;
    bool isend = (l >= nvalid - 1) || (dnx != dme);
    unsigned long long endm = __ballot(isend);

    // ---- register exact-run segmented reduce (num & den together) ----
    #pragma unroll
    for (int i2 = 0; i2 < 2; ++i2) {
      const int c = (w + 4 * i2) * 16 + ccol;
      float ptn = 0.f, ptd = 0.f;         // prev m-tile tail (valid in g4==3)
      #pragma unroll
      for (int mt = 0; mt < 4; ++mt) {
        const int A = mt * 16 + rbase;    // abs start row of lane's chunk
        // per-row contributions (zeroed past nvalid)
        float vn[4], vd[4];
        #pragma unroll
        for (int r = 0; r < 4; ++r) {
          float lg = acc[mt][i2][r];
          float e_ = __expf(lg >= 0.f ? lg : slope * lg);
          bool ok = (A + r) < nvalid;
          vd[r] = ok ? e_ : 0.f;
          vn[r] = ok ? e_ * acc[mt][i2 + 2][r] : 0.f;
        }
        // local pass: flush complete interior runs, keep first-seg + tail
        float tn = 0.f, td = 0.f, fn = 0.f, fd = 0.f;
        int firstrow = -1;
        #pragma unroll
        for (int r = 0; r < 4; ++r) {
          tn += vn[r]; td += vd[r];
          if ((endm >> (A + r)) & 1ull) {
            if (firstrow < 0) {
              fn = tn; fd = td; firstrow = A + r;
            } else {
              int dd = s_dst[A + r];
              unsafeAtomicAdd(&num[(size_t)dd * 128 + c], tn);
              unsafeAtomicAdd(&den[(size_t)dd * 128 + c], td);
            }
            tn = 0.f; td = 0.f;
          }
        }
        const bool seen = (firstrow >= 0);
        // carry chain across quarters (and from previous m-tile into g4==0)
        const bool cont_tile =
            (mt > 0) && !((endm >> (mt * 16 - 1)) & 1ull);  // wave-uniform
        float cin_n = __shfl(ptn, (l & 15) + 48);
        float cin_d = __shfl(ptd, (l & 15) + 48);
        int shp = (A == 0) ? 0 : (A - 1);                   // safe shift
        bool open_in = (g4 == 0) ? cont_tile
                                 : !((endm >> shp) & 1ull);
        float cn = (g4 == 0 && cont_tile) ? cin_n : 0.f;
        float cd = (g4 == 0 && cont_tile) ? cin_d : 0.f;
        #pragma unroll
        for (int s = 0; s < 3; ++s) {
          float on = seen ? tn : (tn + cn);
          float od = seen ? td : (td + cd);
          float un = __shfl_up(on, 16);
          float ud = __shfl_up(od, 16);
          if (g4 == s + 1) {
            cn = open_in ? un : 0.f;
            cd = open_in ? ud : 0.f;
          }
        }
        // flush first segment with its incoming carry
        if (seen) {
          int dd = s_dst[firstrow];
          unsafeAtomicAdd(&num[(size_t)dd * 128 + c], fn + cn);
          unsafeAtomicAdd(&den[(size_t)dd * 128 + c], fd + cd);
        }
        // tile tail out (consumed from g4==3 lanes next iteration)
        ptn = seen ? tn : (tn + cn);
        ptd = seen ? td : (td + cd);
      }
    }
  }
}

// ---------------------------------------------------------------------------
// K4: finalize (vectorized)
// ---------------------------------------------------------------------------
__global__ void finalize_kernel(const float4* __restrict__ num4,
                                const float4* __restrict__ den4,
                                const float4* __restrict__ bT4,
                                float4* __restrict__ out4, int total4) {
  int i = blockIdx.x * 256 + threadIdx.x;
  if (i < total4) {
    float4 n = num4[i];
    float4 d = den4[i];
    float4 b = bT4[i & 31];
    float4 o;
    o.x = n.x / (d.x + 1e-16f) + b.x;
    o.y = n.y / (d.y + 1e-16f) + b.y;
    o.z = n.z / (d.z + 1e-16f) + b.z;
    o.w = n.w / (d.w + 1e-16f) + b.w;
    out4[i] = o;
  }
}

extern "C" void kernel_launch(void* const* d_in, const int* in_sizes, int n_in,
                              void* d_out, int out_size, void* d_ws, size_t ws_size,
                              hipStream_t stream) {
  const float* x   = (const float*)d_in[0];
  const int*   ei  = (const int*)d_in[1];
  const float* ea  = (const float*)d_in[2];
  const float* Wa  = (const float*)d_in[3];
  const float* Wt  = (const float*)d_in[4];
  const float* bT  = (const float*)d_in[5];
  const float* We  = (const float*)d_in[6];
  const float* Wee = (const float*)d_in[7];
  const float* ap  = (const float*)d_in[8];

  const int N = in_sizes[0] / 128;          // 50000
  const int E = in_sizes[1] / 2;            // 500000
  const int NB = (N + 255) / 256;           // 196

  // workspace layout (byte offsets)
  char* ws = (char*)d_ws;
  unsigned short* Bp = (unsigned short*)ws;                       // 204,800
  float* num = (float*)(ws + 204800);                             // 25.6 MB
  float* den = num + (size_t)N * 128;                             // 25.6 MB
  int* cnt   = (int*)(ws + 204800 + (size_t)N * 128 * 8);         // 200,704
  int* cur   = cnt + 50176;                                       // 200,704
  int2* se_s = (int2*)(cur + 50176);                              // 4 MB
  int* dst_s = (int*)(se_s + 500224);                             // 2 MB
  int* bsum  = dst_s + 500224;                                    // 1 KB
  unsigned short* x_bf16 = (unsigned short*)(bsum + 256);         // 12.8 MB

  float* out_x = (float*)d_out;
  float* out_e = out_x + (size_t)N * 128;

  // zero cnt only (num/den zeroed inside prep grid)
  hipMemsetAsync(cnt, 0, 50176 * sizeof(int), stream);

  // K1: hist + zero num/den + x->bf16 + B-pack
  {
    int H = (E + 255) >> 8;
    int Z = (N * 64 + 255) >> 8;
    int X = (N * 32 + 255) >> 8;
    prep_kernel<<<H + Z + X + 400, 256, 0, stream>>>(
        ei, x, Wa, Wt, We, Wee, cnt, (float4*)num, x_bf16, Bp, E, N);
  }

  // K2: scans (tiny)
  scan1_kernel<<<NB, 256, 0, stream>>>(cnt, bsum, N);
  scan2_kernel<<<1, 256, 0, stream>>>(bsum, NB);
  scan3_kernel<<<NB, 256, 0, stream>>>(cnt, bsum, cur, N);

  // K3: scatter at full TLP
  scatter_kernel<<<(E + 255) / 256, 256, 0, stream>>>(ei, cur, se_s, dst_s, E);

  // K4: fused gather + GEMM + register segmented reduce
  fused_edge_kernel<<<(E + 63) / 64, 256, 0, stream>>>(
      x_bf16, ea, se_s, dst_s, Bp, num, den, out_e, ap, E);

  // K5: finalize
  finalize_kernel<<<(N * 32 + 255) / 256, 256, 0, stream>>>(
      (const float4*)num, (const float4*)den, (const float4*)bT,
      (float4*)d_out, N * 32);
}